// Round 7
// baseline (521.866 us; speedup 1.0000x reference)
//
#include <hip/hip_runtime.h>
#include <hip/hip_fp16.h>

// Stacked GRU (T=50, B=1, H=256) on MI355X — round 7.
// Dual-path exchange (fast: same-XCD L2 atomics, slow: agent-scope tags) with
// f16-packed h (2 values per u64 -> half the atomic traffic), Gx prefetched
// into LDS by wave3 (off the critical path), rebalanced dot waves, and fast
// sigmoid/tanh. Election of 32 scan blocks onto one XCD as in round 6.

#define T_STEPS 50
#define VIN 768
#define VF 128
#define MIN_ 2
#define H 256
#define G3 768

#define NB 32
#define BT 256
#define HJ 8
#define ROWS 24
#define WSLICE (4*ROWS*256)
#define BAIL 4000000
#define NBLOCKS 264

typedef unsigned long long u64;

__device__ __forceinline__ float sigm(float x){
  x = fminf(fmaxf(x, -30.f), 30.f);
  return __builtin_amdgcn_rcpf(1.f + __expf(-x));
}
__device__ __forceinline__ float ftanh(float x){
  x = fminf(fmaxf(x, -9.f), 9.f);
  float e = __expf(2.f*x);
  return (e - 1.f) * __builtin_amdgcn_rcpf(e + 1.f);
}
__device__ __forceinline__ float eluf(float x){ return x > 0.0f ? x : expm1f(x); }

__device__ __forceinline__ u64 ald(const u64* p){
  return __hip_atomic_load(const_cast<u64*>(p), __ATOMIC_RELAXED, __HIP_MEMORY_SCOPE_AGENT);
}
__device__ __forceinline__ void ast(u64* p, u64 v){
  __hip_atomic_store(p, v, __ATOMIC_RELAXED, __HIP_MEMORY_SCOPE_AGENT);
}
__device__ __forceinline__ u64 packtv(unsigned tag, float v){
  union{ float f; unsigned u; } c; c.f = v;
  return ((u64)tag << 32) | (u64)c.u;
}
__device__ __forceinline__ float unpackv(u64 x){
  union{ unsigned u; float f; } c; c.u = (unsigned)x; return c.f;
}

// fast poll (f16-packed): 2 returning L2 atomics per lane per iteration.
// entry e <-> h[2e], h[2e+1]; lane handles e=lane and e=64+lane.
__device__ __forceinline__ bool poll_fast16(u64* base, int lane, unsigned tag, float* h, int tries){
  u64* p = base + lane;
  u64 zero = 0;
  for (int i = 0; i < tries; ++i){
    u64 x0, x1;
    asm volatile(
      "global_atomic_add_x2 %0, %2, %4, off sc0\n\t"
      "global_atomic_add_x2 %1, %3, %4, off sc0\n\t"
      "s_waitcnt vmcnt(0)"
      : "=&v"(x0), "=&v"(x1)
      : "v"(p), "v"(p+64), "v"(zero)
      : "memory");
    bool ok = (((unsigned)(x0>>32))==tag) & (((unsigned)(x1>>32))==tag);
    if (__all(ok)){
      union{ unsigned u; __half2 hh; } c0, c1;
      c0.u = (unsigned)x0; c1.u = (unsigned)x1;
      float2 f0 = __half22float2(c0.hh);
      float2 f1 = __half22float2(c1.hh);
      h[2*lane]       = f0.x;  h[2*lane + 1]   = f0.y;
      h[128 + 2*lane] = f1.x;  h[129 + 2*lane] = f1.y;
      return true;
    }
  }
  return false;
}

// slow poll: agent-scope grouped loads on the f32 tagged array (proven path).
__device__ __forceinline__ void poll_slow(const u64* base, int lane, unsigned tag, float* h){
  const u64* p = base + lane;
  int guard = 0;
  while (true){
    u64 x0 = ald(p), x1 = ald(p+64), x2 = ald(p+128), x3 = ald(p+192);
    bool ok = (((unsigned)(x0>>32))==tag) & (((unsigned)(x1>>32))==tag)
            & (((unsigned)(x2>>32))==tag) & (((unsigned)(x3>>32))==tag);
    if (ok | (++guard > BAIL)){
      h[      lane] = unpackv(x0);
      h[ 64 + lane] = unpackv(x1);
      h[128 + lane] = unpackv(x2);
      h[192 + lane] = unpackv(x3);
      break;
    }
    if (guard > 2000) __builtin_amdgcn_s_sleep(1);
  }
}

// nrows row-dots of one 24x256 f16 slice; lane's 4 swizzled cols are
// {lane, 64+lane, 128+lane, 192+lane}; lane0 writes out[lr].
__device__ __forceinline__ void dot_rows(const __half* wm, float a0, float a1, float a2, float a3,
                                         float* out, int base_lr, int nrows, int lane){
  #pragma unroll
  for (int rr = 0; rr < nrows; ++rr){
    const int lr = base_lr + rr;
    const __half2* w = reinterpret_cast<const __half2*>(wm + (lr << 8));
    float2 f0 = __half22float2(w[2*lane]);
    float2 f1 = __half22float2(w[2*lane+1]);
    float s = f0.x*a0 + f0.y*a1 + f1.x*a2 + f1.y*a3;
    #pragma unroll
    for (int off = 32; off; off >>= 1) s += __shfl_xor(s, off);
    if (lane == 0) out[lr] = s;
  }
}

__global__ __launch_bounds__(BT) void fused_kernel(
    const float* __restrict__ v0, const float* __restrict__ m0,
    const float* __restrict__ W1v, const float* __restrict__ b1v,
    const float* __restrict__ W1m, const float* __restrict__ b1m,
    const float* __restrict__ Wih_low, const float* __restrict__ Whh_low,
    const float* __restrict__ bih_low, const float* __restrict__ bhh_low,
    const float* __restrict__ Wih_high, const float* __restrict__ Whh_high,
    const float* __restrict__ bih_high, const float* __restrict__ bhh_high,
    const float* __restrict__ W2v, const float* __restrict__ b2v,
    const float* __restrict__ W2m, const float* __restrict__ b2m,
    float* __restrict__ out,
    u64* h1xf, u64* h2xf, u64* h1xs, u64* h2xs,
    u64* gxt, u64* h1ot, unsigned* ectl)
{
  __shared__ __half w_lds[WSLICE];
  __shared__ float h1n[H], h2n[H];
  __shared__ float gA[2*ROWS], gB[2*ROWS];
  __shared__ float gx_lds[2*ROWS];          // double-buffered Gx slice [par][24]
  __shared__ float xbuf[H];
  __shared__ int s_role, s_idx;

  const int tid = threadIdx.x;
  const int wv = tid >> 6, lane = tid & 63;

  // ---------------- election: find one XCD with >=32 blocks (pigeonhole) ----
  if (tid == 0){
    unsigned xcd;
    asm volatile("s_getreg_b32 %0, hwreg(HW_REG_XCC_ID, 0, 32)" : "=s"(xcd));
    xcd &= 7u;
    unsigned tk = atomicAdd(&ectl[xcd], 1u);
    if (tk == 31u) atomicCAS(&ectl[8], 0u, xcd + 1u);
    unsigned ch; int guard = 0;
    while (!(ch = __hip_atomic_load(&ectl[8], __ATOMIC_RELAXED, __HIP_MEMORY_SCOPE_AGENT))){
      __builtin_amdgcn_s_sleep(2);
      if (++guard > BAIL){ ch = 1u; break; }
    }
    if (xcd == ch - 1u && tk < 32u){ s_role = 0; s_idx = (int)tk; }
    else {
      unsigned ak = atomicAdd(&ectl[9], 1u);
      if      (ak < 50u ){ s_role = 1; s_idx = (int)ak; }
      else if (ak < 100u){ s_role = 2; s_idx = (int)(ak - 50u); }
      else               { s_role = 3; s_idx = 0; }
    }
  }
  __syncthreads();
  const int role = s_role, idx = s_idx;
  if (role == 3) return;

  if (role == 0){
    // ================================================== scan role
    const int b = idx;
    for (int i = tid; i < WSLICE; i += BT){
      int c_sw = i & 255;
      int r2 = i >> 8;
      int lr = r2 % ROWS, m = r2 / ROWS;
      int c = (c_sw & 3)*64 + (c_sw >> 2);
      int g = lr / HJ, j = lr % HJ;
      int row = g*H + b*HJ + j;
      float v;
      if      (m == 0) v = Wih_low [row*(2*H) + H + c];
      else if (m == 1) v = Whh_low [row*H + c];
      else if (m == 2) v = Wih_high[row*H + c];
      else             v = Whh_high[row*H + c];
      w_lds[i] = __float2half(v);
    }
    if (tid < H) h2n[tid] = 0.f;
    if (tid < 2*ROWS) gA[tid] = 0.f;

    const __half* w_m0 = w_lds;               // Wih_low[:,256:512] (gi_A)
    const __half* w_m1 = w_lds + 1*ROWS*256;  // Whh_low   (gh_A)
    const __half* w_m2 = w_lds + 2*ROWS*256;  // Wih_high  (gi_B)
    const __half* w_m3 = w_lds + 3*ROWS*256;  // Whh_high  (gh_B)

    float hv1 = 0.f, hv2 = 0.f;
    float blR=0,blZ=0,blN=0, biR=0,biZ=0,biN=0, bhR=0,bhZ=0,bhN=0;
    bool fast_ok = true;                      // latched by wave0
    const int jg = b*HJ + lane;               // valid for lane<HJ
    if (wv == 0 && lane < HJ){
      blR = bhh_low [jg]; blZ = bhh_low [H+jg]; blN = bhh_low [2*H+jg];
      biR = bih_high[jg]; biZ = bih_high[H+jg]; biN = bih_high[2*H+jg];
      bhR = bhh_high[jg]; bhZ = bhh_high[H+jg]; bhN = bhh_high[2*H+jg];
      const u64* g = gxt + jg;                // Gx[0] -> gx_lds[0]
      int guard = 0;
      while (true){
        u64 a0 = ald(g), a1 = ald(g + H), a2 = ald(g + 2*H);
        bool ok = (((unsigned)(a0>>32))==1u) & (((unsigned)(a1>>32))==1u) & (((unsigned)(a2>>32))==1u);
        if (ok | (++guard > BAIL)){
          gx_lds[lane] = unpackv(a0); gx_lds[8+lane] = unpackv(a1); gx_lds[16+lane] = unpackv(a2);
          break;
        }
        __builtin_amdgcn_s_sleep(4);
      }
    }
    __syncthreads();

    for (int t = 0; t < T_STEPS; ++t){
      const int par = t & 1;
      const unsigned tag = (unsigned)(t + 1);

      // ---- seg1: wave0 finalize A + dual publish + poll h1 | waves1-2 gh_B | wave3 Gx[t+1]
      if (wv == 0){
        float hnew = hv1;
        if (lane < HJ){
          float giR = gA[lane]      + gx_lds[par*ROWS + lane];
          float giZ = gA[HJ+lane]   + gx_lds[par*ROWS + HJ + lane];
          float giN = gA[2*HJ+lane] + gx_lds[par*ROWS + 2*HJ + lane];
          float ghR = gA[ROWS+lane]      + blR;
          float ghZ = gA[ROWS+HJ+lane]   + blZ;
          float ghN = gA[ROWS+2*HJ+lane] + blN;
          float r = sigm(giR + ghR), z = sigm(giZ + ghZ);
          float n = ftanh(giN + r * ghN);
          hv1 = (1.f - z) * n + z * hv1;
          hnew = hv1;
          ast(h1ot + (size_t)t*H + jg, packtv(1u, hv1));   // cross-XCD to post
        }
        // pack pairs on lanes 0..3 and publish fast(+slow)
        float pa = __shfl(hnew, 2*(lane & 3));
        float pb = __shfl(hnew, 2*(lane & 3) + 1);
        if (lane < 4){
          union{ __half2 hh; unsigned u; } c; c.hh = __floats2half2_rn(pa, pb);
          u64 pk = ((u64)tag << 32) | (u64)c.u;
          u64* df = h1xf + par*128 + (b<<2) + lane;
          #pragma unroll
          for (int cc = 0; cc < NB; ++cc)
            asm volatile("global_atomic_swap_x2 %0, %1, off" :: "v"(df + cc*256), "v"(pk) : "memory");
        }
        if (lane < HJ) ast(h1xs + par*H + jg, packtv(tag, hv1));
      } else if (wv < 3){
        float a0=h2n[lane], a1=h2n[64+lane], a2=h2n[128+lane], a3=h2n[192+lane];
        dot_rows(w_m3, a0,a1,a2,a3, gB + ROWS, (wv-1)*12, 12, lane);   // gh_B
      } else {
        if (t + 1 < T_STEPS && lane < HJ){                 // prefetch Gx[t+1] -> gx_lds[1-par]
          const u64* g = gxt + (size_t)(t+1)*G3 + jg;
          int guard = 0;
          while (true){
            u64 a0 = ald(g), a1 = ald(g + H), a2 = ald(g + 2*H);
            bool ok = (((unsigned)(a0>>32))==1u) & (((unsigned)(a1>>32))==1u) & (((unsigned)(a2>>32))==1u);
            if (ok | (++guard > BAIL)){
              int np = (1 - par) * ROWS;
              gx_lds[np + lane] = unpackv(a0); gx_lds[np + 8 + lane] = unpackv(a1); gx_lds[np + 16 + lane] = unpackv(a2);
              break;
            }
            __builtin_amdgcn_s_sleep(1);
          }
        }
      }
      if (t == T_STEPS - 1) break;
      if (wv == 0){
        bool got = false;
        if (fast_ok){
          got = poll_fast16(h1xf + b*256 + par*128, lane, tag, h1n, t==0 ? 6000 : 300000);
          fast_ok = got;
        }
        if (!got) poll_slow(h1xs + par*H, lane, tag, h1n);
      }
      __syncthreads();                                   // sync1: h1n, gh_B, gx[t+1] ready

      // ---- seg2: gi_B on all 4 waves (6 rows each)
      { float a0=h1n[lane], a1=h1n[64+lane], a2=h1n[128+lane], a3=h1n[192+lane];
        dot_rows(w_m2, a0,a1,a2,a3, gB, wv*6, 6, lane); }
      __syncthreads();                                   // sync2: gB complete

      // ---- seg3: wave0 finalize B + dual publish + poll h2 | waves1-3 gh_A'
      if (wv == 0){
        float hnew = hv2;
        if (lane < HJ){
          float giR = gB[lane]      + biR, ghR = gB[ROWS+lane]      + bhR;
          float giZ = gB[HJ+lane]   + biZ, ghZ = gB[ROWS+HJ+lane]   + bhZ;
          float giN = gB[2*HJ+lane] + biN, ghN = gB[ROWS+2*HJ+lane] + bhN;
          float r = sigm(giR + ghR), z = sigm(giZ + ghZ);
          float n = ftanh(giN + r * ghN);
          hv2 = (1.f - z) * n + z * hv2;
          hnew = hv2;
        }
        float pa = __shfl(hnew, 2*(lane & 3));
        float pb = __shfl(hnew, 2*(lane & 3) + 1);
        if (lane < 4){
          union{ __half2 hh; unsigned u; } c; c.hh = __floats2half2_rn(pa, pb);
          u64 pk = ((u64)tag << 32) | (u64)c.u;
          u64* df = h2xf + par*128 + (b<<2) + lane;
          #pragma unroll
          for (int cc = 0; cc < NB; ++cc)
            asm volatile("global_atomic_swap_x2 %0, %1, off" :: "v"(df + cc*256), "v"(pk) : "memory");
        }
        if (lane < HJ) ast(h2xs + par*H + jg, packtv(tag, hv2));
        bool got = false;
        if (fast_ok){
          got = poll_fast16(h2xf + b*256 + par*128, lane, tag, h2n, 300000);
          fast_ok = got;
        }
        if (!got) poll_slow(h2xs + par*H, lane, tag, h2n);
      } else {
        float a0=h1n[lane], a1=h1n[64+lane], a2=h1n[128+lane], a3=h1n[192+lane];
        dot_rows(w_m1, a0,a1,a2,a3, gA + ROWS, (wv-1)*8, 8, lane);   // gh_A'
      }
      __syncthreads();                                   // sync3: h2n + gh_A' ready

      // ---- seg4: gi_A' on all 4 waves (6 rows each)
      { float a0=h2n[lane], a1=h2n[64+lane], a2=h2n[128+lane], a3=h2n[192+lane];
        dot_rows(w_m0, a0,a1,a2,a3, gA, wv*6, 6, lane); }
      __syncthreads();                                   // sync4
    }

  } else if (role == 1){
    // ================================================== featgx role
    const int t = idx;
    { int j = tid >> 1, s = tid & 1;
      const float4* a4 = reinterpret_cast<const float4*>(v0 + (size_t)t*VIN) + s*96;
      const float4* w4 = reinterpret_cast<const float4*>(W1v + (size_t)j*VIN) + s*96;
      float p = 0.f;
      #pragma unroll 4
      for (int c = 0; c < 96; ++c){
        float4 a = a4[c], w = w4[c];
        p += a.x*w.x + a.y*w.y + a.z*w.z + a.w*w.w;
      }
      p += __shfl_xor(p, 1);
      if (s == 0) xbuf[j] = eluf(p + b1v[j]);
    }
    if (tid < VF){
      float am = b1m[tid] + W1m[tid*2]*m0[t*2] + W1m[tid*2+1]*m0[t*2+1];
      xbuf[VF + tid] = eluf(am);
    }
    __syncthreads();
    #pragma unroll
    for (int k = 0; k < 3; ++k){
      int r = k*256 + tid;
      const float4* w4 = reinterpret_cast<const float4*>(Wih_low + (size_t)r*(2*H));
      const float4* x4 = reinterpret_cast<const float4*>(xbuf);
      float acc = bih_low[r];
      #pragma unroll 8
      for (int c = 0; c < 64; ++c){
        float4 w = w4[c], x = x4[c];
        acc += w.x*x.x + w.y*x.y + w.z*x.z + w.w*x.w;
      }
      ast(gxt + (size_t)t*G3 + r, packtv(1u, acc));
    }

  } else {
    // ================================================== post role
    const int t = idx;
    for (int i = 0; i < t; ++i) __builtin_amdgcn_s_sleep(32);   // staggered start
    if (wv == 0){
      const u64* p = h1ot + (size_t)t*H + lane;
      int guard = 0;
      while (true){
        u64 x0 = ald(p), x1 = ald(p+64), x2 = ald(p+128), x3 = ald(p+192);
        bool ok = (((unsigned)(x0>>32))==1u) & (((unsigned)(x1>>32))==1u)
                & (((unsigned)(x2>>32))==1u) & (((unsigned)(x3>>32))==1u);
        if (ok | (++guard > BAIL)){
          xbuf[      lane] = eluf(unpackv(x0));
          xbuf[ 64 + lane] = eluf(unpackv(x1));
          xbuf[128 + lane] = eluf(unpackv(x2));
          xbuf[192 + lane] = eluf(unpackv(x3));
          break;
        }
        __builtin_amdgcn_s_sleep(8);
      }
    }
    __syncthreads();
    #pragma unroll
    for (int k = 0; k < 3; ++k){
      int r = k*256 + tid;
      const float4* w4 = reinterpret_cast<const float4*>(W2v + (size_t)r*VF);
      const float4* f4 = reinterpret_cast<const float4*>(xbuf);
      float acc = b2v[r];
      #pragma unroll 8
      for (int c = 0; c < 32; ++c){
        float4 w = w4[c], x = f4[c];
        acc += w.x*x.x + w.y*x.y + w.z*x.z + w.w*x.w;
      }
      out[(size_t)t*VIN + r] = sigm(acc);
    }
    if (tid < MIN_){
      const float* wm = W2m + tid*VF;
      float am = b2m[tid];
      #pragma unroll 8
      for (int c = 0; c < VF; ++c) am += wm[c] * xbuf[VF + c];
      out[(size_t)T_STEPS*VIN + t*MIN_ + tid] = tanhf(am);
    }
  }
}

extern "C" void kernel_launch(void* const* d_in, const int* in_sizes, int n_in,
                              void* d_out, int out_size, void* d_ws, size_t ws_size,
                              hipStream_t stream)
{
  const float* v0       = (const float*)d_in[0];
  const float* m0       = (const float*)d_in[1];
  const float* W1v      = (const float*)d_in[2];
  const float* b1v      = (const float*)d_in[3];
  const float* W1m      = (const float*)d_in[4];
  const float* b1m      = (const float*)d_in[5];
  const float* Wih_low  = (const float*)d_in[6];
  const float* Whh_low  = (const float*)d_in[7];
  const float* bih_low  = (const float*)d_in[8];
  const float* bhh_low  = (const float*)d_in[9];
  const float* Wih_high = (const float*)d_in[10];
  const float* Whh_high = (const float*)d_in[11];
  const float* bih_high = (const float*)d_in[12];
  const float* bhh_high = (const float*)d_in[13];
  const float* W2v      = (const float*)d_in[14];
  const float* b2v      = (const float*)d_in[15];
  const float* W2m      = (const float*)d_in[16];
  const float* b2m      = (const float*)d_in[17];
  float* out = (float*)d_out;

  // ws layout (8B-aligned). Poison 0xAA..AA != any tag used (1..50).
  // h1xf/h2xf (fast, f16-packed): [copy c][par][128] u64 -> copy c at c*256.
  // h1xs/h2xs (slow, f32 tagged): [par][256] u64, single shared copy.
  char* ws = (char*)d_ws;
  u64* h1xf     = (u64*)(ws + 0);               // 64 KB
  u64* h2xf     = (u64*)(ws + 65536);           // 64 KB
  u64* h1xs     = (u64*)(ws + 131072);          // 4 KB
  u64* h2xs     = (u64*)(ws + 135168);          // 4 KB
  u64* gxt      = (u64*)(ws + 139264);          // 300 KB
  u64* h1ot     = (u64*)(ws + 446464);          // 100 KB
  unsigned* ectl= (unsigned*)(ws + 548864);     // election counters

  hipMemsetAsync(ws + 548864, 0, 256, stream);  // zero election state only

  fused_kernel<<<NBLOCKS, BT, 0, stream>>>(
      v0, m0, W1v, b1v, W1m, b1m,
      Wih_low, Whh_low, bih_low, bhh_low,
      Wih_high, Whh_high, bih_high, bhh_high,
      W2v, b2v, W2m, b2m, out,
      h1xf, h2xf, h1xs, h2xs, gxt, h1ot, ectl);
}

// Round 8
// 518.592 us; speedup vs baseline: 1.0063x; 1.0063x over previous
//
#include <hip/hip_runtime.h>
#include <hip/hip_fp16.h>

// Stacked GRU (T=50, B=1, H=256) on MI355X — round 8.
// Identical scan/featgx/post structure to round 7 (passed, absmax 3.9e-3).
// NEW: "heater" blocks — all blocks without pending real work spin register
// FMAs until the scan completes (per-XCD done flags), so the DPM governor
// sees a busy chip and holds high engine clock. Scan waves run at s_setprio 3,
// heaters at 0, so co-resident heaters can't steal issue slots from the scan.

#define T_STEPS 50
#define VIN 768
#define VF 128
#define MIN_ 2
#define H 256
#define G3 768

#define NB 32
#define BT 256
#define HJ 8
#define ROWS 24
#define WSLICE (4*ROWS*256)
#define BAIL 4000000
#define NBLOCKS 264

typedef unsigned long long u64;

__device__ __forceinline__ float sigm(float x){
  x = fminf(fmaxf(x, -30.f), 30.f);
  return __builtin_amdgcn_rcpf(1.f + __expf(-x));
}
__device__ __forceinline__ float ftanh(float x){
  x = fminf(fmaxf(x, -9.f), 9.f);
  float e = __expf(2.f*x);
  return (e - 1.f) * __builtin_amdgcn_rcpf(e + 1.f);
}
__device__ __forceinline__ float eluf(float x){ return x > 0.0f ? x : expm1f(x); }

__device__ __forceinline__ u64 ald(const u64* p){
  return __hip_atomic_load(const_cast<u64*>(p), __ATOMIC_RELAXED, __HIP_MEMORY_SCOPE_AGENT);
}
__device__ __forceinline__ void ast(u64* p, u64 v){
  __hip_atomic_store(p, v, __ATOMIC_RELAXED, __HIP_MEMORY_SCOPE_AGENT);
}
__device__ __forceinline__ u64 packtv(unsigned tag, float v){
  union{ float f; unsigned u; } c; c.f = v;
  return ((u64)tag << 32) | (u64)c.u;
}
__device__ __forceinline__ float unpackv(u64 x){
  union{ unsigned u; float f; } c; c.u = (unsigned)x; return c.f;
}

// heater: 4 independent FMA chains, check per-XCD done flag every ~8k instrs.
__device__ __forceinline__ void heat(unsigned* done, unsigned xcd, float* sink){
  asm volatile("s_setprio 0");
  float a = 1.0f + (float)threadIdx.x, b = 2.0f, c = 3.0f, d = 4.0f;
  const float k = 1.0000001f, e = 1.1920929e-07f;
  for (int g = 0; g < 20000; ++g){
    #pragma unroll 16
    for (int i = 0; i < 1024; ++i){
      a = __builtin_fmaf(a, k, e);
      b = __builtin_fmaf(b, k, e);
      c = __builtin_fmaf(c, k, e);
      d = __builtin_fmaf(d, k, e);
    }
    if (__hip_atomic_load(done + (xcd & 7u), __ATOMIC_RELAXED, __HIP_MEMORY_SCOPE_AGENT)) break;
  }
  float x = a + b + c + d;
  if (x == 1.2345f) *sink = x;   // unreachable in practice; keeps chains alive
}

// fast poll (f16-packed): 2 returning L2 atomics per lane per iteration.
__device__ __forceinline__ bool poll_fast16(u64* base, int lane, unsigned tag, float* h, int tries){
  u64* p = base + lane;
  u64 zero = 0;
  for (int i = 0; i < tries; ++i){
    u64 x0, x1;
    asm volatile(
      "global_atomic_add_x2 %0, %2, %4, off sc0\n\t"
      "global_atomic_add_x2 %1, %3, %4, off sc0\n\t"
      "s_waitcnt vmcnt(0)"
      : "=&v"(x0), "=&v"(x1)
      : "v"(p), "v"(p+64), "v"(zero)
      : "memory");
    bool ok = (((unsigned)(x0>>32))==tag) & (((unsigned)(x1>>32))==tag);
    if (__all(ok)){
      union{ unsigned u; __half2 hh; } c0, c1;
      c0.u = (unsigned)x0; c1.u = (unsigned)x1;
      float2 f0 = __half22float2(c0.hh);
      float2 f1 = __half22float2(c1.hh);
      h[2*lane]       = f0.x;  h[2*lane + 1]   = f0.y;
      h[128 + 2*lane] = f1.x;  h[129 + 2*lane] = f1.y;
      return true;
    }
  }
  return false;
}

// slow poll: agent-scope grouped loads on the f32 tagged array (proven path).
__device__ __forceinline__ void poll_slow(const u64* base, int lane, unsigned tag, float* h){
  const u64* p = base + lane;
  int guard = 0;
  while (true){
    u64 x0 = ald(p), x1 = ald(p+64), x2 = ald(p+128), x3 = ald(p+192);
    bool ok = (((unsigned)(x0>>32))==tag) & (((unsigned)(x1>>32))==tag)
            & (((unsigned)(x2>>32))==tag) & (((unsigned)(x3>>32))==tag);
    if (ok | (++guard > BAIL)){
      h[      lane] = unpackv(x0);
      h[ 64 + lane] = unpackv(x1);
      h[128 + lane] = unpackv(x2);
      h[192 + lane] = unpackv(x3);
      break;
    }
    if (guard > 2000) __builtin_amdgcn_s_sleep(1);
  }
}

// nrows row-dots of one 24x256 f16 slice; lane's 4 swizzled cols are
// {lane, 64+lane, 128+lane, 192+lane}; lane0 writes out[lr].
__device__ __forceinline__ void dot_rows(const __half* wm, float a0, float a1, float a2, float a3,
                                         float* out, int base_lr, int nrows, int lane){
  #pragma unroll
  for (int rr = 0; rr < nrows; ++rr){
    const int lr = base_lr + rr;
    const __half2* w = reinterpret_cast<const __half2*>(wm + (lr << 8));
    float2 f0 = __half22float2(w[2*lane]);
    float2 f1 = __half22float2(w[2*lane+1]);
    float s = f0.x*a0 + f0.y*a1 + f1.x*a2 + f1.y*a3;
    #pragma unroll
    for (int off = 32; off; off >>= 1) s += __shfl_xor(s, off);
    if (lane == 0) out[lr] = s;
  }
}

__global__ __launch_bounds__(BT) void fused_kernel(
    const float* __restrict__ v0, const float* __restrict__ m0,
    const float* __restrict__ W1v, const float* __restrict__ b1v,
    const float* __restrict__ W1m, const float* __restrict__ b1m,
    const float* __restrict__ Wih_low, const float* __restrict__ Whh_low,
    const float* __restrict__ bih_low, const float* __restrict__ bhh_low,
    const float* __restrict__ Wih_high, const float* __restrict__ Whh_high,
    const float* __restrict__ bih_high, const float* __restrict__ bhh_high,
    const float* __restrict__ W2v, const float* __restrict__ b2v,
    const float* __restrict__ W2m, const float* __restrict__ b2m,
    float* __restrict__ out,
    u64* h1xf, u64* h2xf, u64* h1xs, u64* h2xs,
    u64* gxt, u64* h1ot, unsigned* ectl)
{
  __shared__ __half w_lds[WSLICE];
  __shared__ float h1n[H], h2n[H];
  __shared__ float gA[2*ROWS], gB[2*ROWS];
  __shared__ float gx_lds[2*ROWS];          // double-buffered Gx slice [par][24]
  __shared__ float xbuf[H];
  __shared__ int s_role, s_idx, s_xcd;

  const int tid = threadIdx.x;
  const int wv = tid >> 6, lane = tid & 63;
  unsigned* done = ectl + 16;               // 8 per-XCD done replicas (zeroed)
  float* sink = (float*)(ectl + 32);

  // ---------------- election: find one XCD with >=32 blocks (pigeonhole) ----
  if (tid == 0){
    unsigned xcd;
    asm volatile("s_getreg_b32 %0, hwreg(HW_REG_XCC_ID, 0, 32)" : "=s"(xcd));
    xcd &= 7u;
    s_xcd = (int)xcd;
    unsigned tk = atomicAdd(&ectl[xcd], 1u);
    if (tk == 31u) atomicCAS(&ectl[8], 0u, xcd + 1u);
    unsigned ch; int guard = 0;
    while (!(ch = __hip_atomic_load(&ectl[8], __ATOMIC_RELAXED, __HIP_MEMORY_SCOPE_AGENT))){
      __builtin_amdgcn_s_sleep(2);
      if (++guard > BAIL){ ch = 1u; break; }
    }
    if (xcd == ch - 1u && tk < 32u){ s_role = 0; s_idx = (int)tk; }
    else {
      unsigned ak = atomicAdd(&ectl[9], 1u);
      if      (ak < 50u ){ s_role = 1; s_idx = (int)ak; }
      else if (ak < 100u){ s_role = 2; s_idx = (int)(ak - 50u); }
      else               { s_role = 3; s_idx = 0; }
    }
  }
  __syncthreads();
  const int role = s_role, idx = s_idx;
  const unsigned myxcd = (unsigned)s_xcd;
  if (role == 3){ heat(done, myxcd, sink); return; }

  if (role == 0){
    // ================================================== scan role
    asm volatile("s_setprio 3");
    const int b = idx;
    for (int i = tid; i < WSLICE; i += BT){
      int c_sw = i & 255;
      int r2 = i >> 8;
      int lr = r2 % ROWS, m = r2 / ROWS;
      int c = (c_sw & 3)*64 + (c_sw >> 2);
      int g = lr / HJ, j = lr % HJ;
      int row = g*H + b*HJ + j;
      float v;
      if      (m == 0) v = Wih_low [row*(2*H) + H + c];
      else if (m == 1) v = Whh_low [row*H + c];
      else if (m == 2) v = Wih_high[row*H + c];
      else             v = Whh_high[row*H + c];
      w_lds[i] = __float2half(v);
    }
    if (tid < H) h2n[tid] = 0.f;
    if (tid < 2*ROWS) gA[tid] = 0.f;

    const __half* w_m0 = w_lds;               // Wih_low[:,256:512] (gi_A)
    const __half* w_m1 = w_lds + 1*ROWS*256;  // Whh_low   (gh_A)
    const __half* w_m2 = w_lds + 2*ROWS*256;  // Wih_high  (gi_B)
    const __half* w_m3 = w_lds + 3*ROWS*256;  // Whh_high  (gh_B)

    float hv1 = 0.f, hv2 = 0.f;
    float blR=0,blZ=0,blN=0, biR=0,biZ=0,biN=0, bhR=0,bhZ=0,bhN=0;
    bool fast_ok = true;                      // latched by wave0
    const int jg = b*HJ + lane;               // valid for lane<HJ
    if (wv == 0 && lane < HJ){
      blR = bhh_low [jg]; blZ = bhh_low [H+jg]; blN = bhh_low [2*H+jg];
      biR = bih_high[jg]; biZ = bih_high[H+jg]; biN = bih_high[2*H+jg];
      bhR = bhh_high[jg]; bhZ = bhh_high[H+jg]; bhN = bhh_high[2*H+jg];
      const u64* g = gxt + jg;                // Gx[0] -> gx_lds[0]
      int guard = 0;
      while (true){
        u64 a0 = ald(g), a1 = ald(g + H), a2 = ald(g + 2*H);
        bool ok = (((unsigned)(a0>>32))==1u) & (((unsigned)(a1>>32))==1u) & (((unsigned)(a2>>32))==1u);
        if (ok | (++guard > BAIL)){
          gx_lds[lane] = unpackv(a0); gx_lds[8+lane] = unpackv(a1); gx_lds[16+lane] = unpackv(a2);
          break;
        }
        __builtin_amdgcn_s_sleep(4);
      }
    }
    __syncthreads();

    for (int t = 0; t < T_STEPS; ++t){
      const int par = t & 1;
      const unsigned tag = (unsigned)(t + 1);

      // ---- seg1: wave0 finalize A + dual publish + poll h1 | waves1-2 gh_B | wave3 Gx[t+1]
      if (wv == 0){
        float hnew = hv1;
        if (lane < HJ){
          float giR = gA[lane]      + gx_lds[par*ROWS + lane];
          float giZ = gA[HJ+lane]   + gx_lds[par*ROWS + HJ + lane];
          float giN = gA[2*HJ+lane] + gx_lds[par*ROWS + 2*HJ + lane];
          float ghR = gA[ROWS+lane]      + blR;
          float ghZ = gA[ROWS+HJ+lane]   + blZ;
          float ghN = gA[ROWS+2*HJ+lane] + blN;
          float r = sigm(giR + ghR), z = sigm(giZ + ghZ);
          float n = ftanh(giN + r * ghN);
          hv1 = (1.f - z) * n + z * hv1;
          hnew = hv1;
          ast(h1ot + (size_t)t*H + jg, packtv(1u, hv1));   // cross-XCD to post
        }
        float pa = __shfl(hnew, 2*(lane & 3));
        float pb = __shfl(hnew, 2*(lane & 3) + 1);
        if (lane < 4){
          union{ __half2 hh; unsigned u; } c; c.hh = __floats2half2_rn(pa, pb);
          u64 pk = ((u64)tag << 32) | (u64)c.u;
          u64* df = h1xf + par*128 + (b<<2) + lane;
          #pragma unroll
          for (int cc = 0; cc < NB; ++cc)
            asm volatile("global_atomic_swap_x2 %0, %1, off" :: "v"(df + cc*256), "v"(pk) : "memory");
        }
        if (lane < HJ) ast(h1xs + par*H + jg, packtv(tag, hv1));
      } else if (wv < 3){
        float a0=h2n[lane], a1=h2n[64+lane], a2=h2n[128+lane], a3=h2n[192+lane];
        dot_rows(w_m3, a0,a1,a2,a3, gB + ROWS, (wv-1)*12, 12, lane);   // gh_B
      } else {
        if (t + 1 < T_STEPS && lane < HJ){                 // prefetch Gx[t+1] -> gx_lds[1-par]
          const u64* g = gxt + (size_t)(t+1)*G3 + jg;
          int guard = 0;
          while (true){
            u64 a0 = ald(g), a1 = ald(g + H), a2 = ald(g + 2*H);
            bool ok = (((unsigned)(a0>>32))==1u) & (((unsigned)(a1>>32))==1u) & (((unsigned)(a2>>32))==1u);
            if (ok | (++guard > BAIL)){
              int np = (1 - par) * ROWS;
              gx_lds[np + lane] = unpackv(a0); gx_lds[np + 8 + lane] = unpackv(a1); gx_lds[np + 16 + lane] = unpackv(a2);
              break;
            }
            __builtin_amdgcn_s_sleep(1);
          }
        }
      }
      if (t == T_STEPS - 1) break;
      if (wv == 0){
        bool got = false;
        if (fast_ok){
          got = poll_fast16(h1xf + b*256 + par*128, lane, tag, h1n, t==0 ? 6000 : 300000);
          fast_ok = got;
        }
        if (!got) poll_slow(h1xs + par*H, lane, tag, h1n);
      }
      __syncthreads();                                   // sync1: h1n, gh_B, gx[t+1] ready

      // ---- seg2: gi_B on all 4 waves (6 rows each)
      { float a0=h1n[lane], a1=h1n[64+lane], a2=h1n[128+lane], a3=h1n[192+lane];
        dot_rows(w_m2, a0,a1,a2,a3, gB, wv*6, 6, lane); }
      __syncthreads();                                   // sync2: gB complete

      // ---- seg3: wave0 finalize B + dual publish + poll h2 | waves1-3 gh_A'
      if (wv == 0){
        float hnew = hv2;
        if (lane < HJ){
          float giR = gB[lane]      + biR, ghR = gB[ROWS+lane]      + bhR;
          float giZ = gB[HJ+lane]   + biZ, ghZ = gB[ROWS+HJ+lane]   + bhZ;
          float giN = gB[2*HJ+lane] + biN, ghN = gB[ROWS+2*HJ+lane] + bhN;
          float r = sigm(giR + ghR), z = sigm(giZ + ghZ);
          float n = ftanh(giN + r * ghN);
          hv2 = (1.f - z) * n + z * hv2;
          hnew = hv2;
        }
        float pa = __shfl(hnew, 2*(lane & 3));
        float pb = __shfl(hnew, 2*(lane & 3) + 1);
        if (lane < 4){
          union{ __half2 hh; unsigned u; } c; c.hh = __floats2half2_rn(pa, pb);
          u64 pk = ((u64)tag << 32) | (u64)c.u;
          u64* df = h2xf + par*128 + (b<<2) + lane;
          #pragma unroll
          for (int cc = 0; cc < NB; ++cc)
            asm volatile("global_atomic_swap_x2 %0, %1, off" :: "v"(df + cc*256), "v"(pk) : "memory");
        }
        if (lane < HJ) ast(h2xs + par*H + jg, packtv(tag, hv2));
        bool got = false;
        if (fast_ok){
          got = poll_fast16(h2xf + b*256 + par*128, lane, tag, h2n, 300000);
          fast_ok = got;
        }
        if (!got) poll_slow(h2xs + par*H, lane, tag, h2n);
      } else {
        float a0=h1n[lane], a1=h1n[64+lane], a2=h1n[128+lane], a3=h1n[192+lane];
        dot_rows(w_m1, a0,a1,a2,a3, gA + ROWS, (wv-1)*8, 8, lane);   // gh_A'
      }
      __syncthreads();                                   // sync3: h2n + gh_A' ready

      // ---- seg4: gi_A' on all 4 waves (6 rows each)
      { float a0=h2n[lane], a1=h2n[64+lane], a2=h2n[128+lane], a3=h2n[192+lane];
        dot_rows(w_m0, a0,a1,a2,a3, gA, wv*6, 6, lane); }
      __syncthreads();                                   // sync4
    }
    // scan complete: block 0 releases the heaters (all 8 XCD replicas)
    if (b == 0 && wv == 0 && lane < 8)
      __hip_atomic_store(done + lane, 1u, __ATOMIC_RELAXED, __HIP_MEMORY_SCOPE_AGENT);

  } else if (role == 1){
    // ================================================== featgx role
    const int t = idx;
    { int j = tid >> 1, s = tid & 1;
      const float4* a4 = reinterpret_cast<const float4*>(v0 + (size_t)t*VIN) + s*96;
      const float4* w4 = reinterpret_cast<const float4*>(W1v + (size_t)j*VIN) + s*96;
      float p = 0.f;
      #pragma unroll 4
      for (int c = 0; c < 96; ++c){
        float4 a = a4[c], w = w4[c];
        p += a.x*w.x + a.y*w.y + a.z*w.z + a.w*w.w;
      }
      p += __shfl_xor(p, 1);
      if (s == 0) xbuf[j] = eluf(p + b1v[j]);
    }
    if (tid < VF){
      float am = b1m[tid] + W1m[tid*2]*m0[t*2] + W1m[tid*2+1]*m0[t*2+1];
      xbuf[VF + tid] = eluf(am);
    }
    __syncthreads();
    #pragma unroll
    for (int k = 0; k < 3; ++k){
      int r = k*256 + tid;
      const float4* w4 = reinterpret_cast<const float4*>(Wih_low + (size_t)r*(2*H));
      const float4* x4 = reinterpret_cast<const float4*>(xbuf);
      float acc = bih_low[r];
      #pragma unroll 8
      for (int c = 0; c < 64; ++c){
        float4 w = w4[c], x = x4[c];
        acc += w.x*x.x + w.y*x.y + w.z*x.z + w.w*x.w;
      }
      ast(gxt + (size_t)t*G3 + r, packtv(1u, acc));
    }
    heat(done, myxcd, sink);

  } else {
    // ================================================== post role
    const int t = idx;
    for (int i = 0; i < t; ++i) __builtin_amdgcn_s_sleep(32);   // staggered start
    if (wv == 0){
      const u64* p = h1ot + (size_t)t*H + lane;
      int guard = 0;
      while (true){
        u64 x0 = ald(p), x1 = ald(p+64), x2 = ald(p+128), x3 = ald(p+192);
        bool ok = (((unsigned)(x0>>32))==1u) & (((unsigned)(x1>>32))==1u)
                & (((unsigned)(x2>>32))==1u) & (((unsigned)(x3>>32))==1u);
        if (ok | (++guard > BAIL)){
          xbuf[      lane] = eluf(unpackv(x0));
          xbuf[ 64 + lane] = eluf(unpackv(x1));
          xbuf[128 + lane] = eluf(unpackv(x2));
          xbuf[192 + lane] = eluf(unpackv(x3));
          break;
        }
        __builtin_amdgcn_s_sleep(8);
      }
    }
    __syncthreads();
    #pragma unroll
    for (int k = 0; k < 3; ++k){
      int r = k*256 + tid;
      const float4* w4 = reinterpret_cast<const float4*>(W2v + (size_t)r*VF);
      const float4* f4 = reinterpret_cast<const float4*>(xbuf);
      float acc = b2v[r];
      #pragma unroll 8
      for (int c = 0; c < 32; ++c){
        float4 w = w4[c], x = f4[c];
        acc += w.x*x.x + w.y*x.y + w.z*x.z + w.w*x.w;
      }
      out[(size_t)t*VIN + r] = sigm(acc);
    }
    if (tid < MIN_){
      const float* wm = W2m + tid*VF;
      float am = b2m[tid];
      #pragma unroll 8
      for (int c = 0; c < VF; ++c) am += wm[c] * xbuf[VF + c];
      out[(size_t)T_STEPS*VIN + t*MIN_ + tid] = tanhf(am);
    }
    heat(done, myxcd, sink);
  }
}

extern "C" void kernel_launch(void* const* d_in, const int* in_sizes, int n_in,
                              void* d_out, int out_size, void* d_ws, size_t ws_size,
                              hipStream_t stream)
{
  const float* v0       = (const float*)d_in[0];
  const float* m0       = (const float*)d_in[1];
  const float* W1v      = (const float*)d_in[2];
  const float* b1v      = (const float*)d_in[3];
  const float* W1m      = (const float*)d_in[4];
  const float* b1m      = (const float*)d_in[5];
  const float* Wih_low  = (const float*)d_in[6];
  const float* Whh_low  = (const float*)d_in[7];
  const float* bih_low  = (const float*)d_in[8];
  const float* bhh_low  = (const float*)d_in[9];
  const float* Wih_high = (const float*)d_in[10];
  const float* Whh_high = (const float*)d_in[11];
  const float* bih_high = (const float*)d_in[12];
  const float* bhh_high = (const float*)d_in[13];
  const float* W2v      = (const float*)d_in[14];
  const float* b2v      = (const float*)d_in[15];
  const float* W2m      = (const float*)d_in[16];
  const float* b2m      = (const float*)d_in[17];
  float* out = (float*)d_out;

  // ws layout (8B-aligned). Poison 0xAA..AA != any tag used (1..50).
  // h1xf/h2xf (fast, f16-packed): [copy c][par][128] u64 -> copy c at c*256.
  // h1xs/h2xs (slow, f32 tagged): [par][256] u64, single shared copy.
  // ectl: [0..7] per-XCD counters, [8] winner, [9] role ticket,
  //       [16..23] per-XCD done flags, [32] heater sink. All zeroed.
  char* ws = (char*)d_ws;
  u64* h1xf     = (u64*)(ws + 0);               // 64 KB
  u64* h2xf     = (u64*)(ws + 65536);           // 64 KB
  u64* h1xs     = (u64*)(ws + 131072);          // 4 KB
  u64* h2xs     = (u64*)(ws + 135168);          // 4 KB
  u64* gxt      = (u64*)(ws + 139264);          // 300 KB
  u64* h1ot     = (u64*)(ws + 446464);          // 100 KB
  unsigned* ectl= (unsigned*)(ws + 548864);     // election + done flags

  hipMemsetAsync(ws + 548864, 0, 256, stream);  // zero election/done state

  fused_kernel<<<NBLOCKS, BT, 0, stream>>>(
      v0, m0, W1v, b1v, W1m, b1m,
      Wih_low, Whh_low, bih_low, bhh_low,
      Wih_high, Whh_high, bih_high, bhh_high,
      W2v, b2v, W2m, b2m, out,
      h1xf, h2xf, h1xs, h2xs, gxt, h1ot, ectl);
}

// Round 9
// 355.324 us; speedup vs baseline: 1.4687x; 1.4595x over previous
//
#include <hip/hip_runtime.h>
#include <hip/hip_fp16.h>

// Stacked GRU (T=50, B=1, H=256) on MI355X — round 9.
// KEY CHANGE: reduction-free dots. Previous rounds threaded ~32 sequential
// row-dots with 6-deep shuffle chains through each step (~4-5us/step of pure
// cross-lane latency) — that, not the exchange, was the plateau. Now each
// matvec phase is ONE parallel pass: 48 rows x 4 lanes/row, K=64/lane via
// packed-f16 v_dot2 (fdot2), 2 shuffles total. Wave3 = dedicated poller,
// wave1 = Gx prefetch. Exchange: round-7 dual path (same-XCD L2 atomics fast
// path via XCC_ID election + agent-scope tagged slow fallback), f16-packed.

#define T_STEPS 50
#define VIN 768
#define VF 128
#define MIN_ 2
#define H 256
#define G3 768

#define NB 32
#define BT 256
#define HJ 8
#define BAIL 4000000
#define NBLOCKS 264

typedef unsigned long long u64;

__device__ __forceinline__ float sigm(float x){
  x = fminf(fmaxf(x, -30.f), 30.f);
  return __builtin_amdgcn_rcpf(1.f + __expf(-x));
}
__device__ __forceinline__ float ftanh(float x){
  x = fminf(fmaxf(x, -9.f), 9.f);
  float e = __expf(2.f*x);
  return (e - 1.f) * __builtin_amdgcn_rcpf(e + 1.f);
}
__device__ __forceinline__ float eluf(float x){ return x > 0.0f ? x : expm1f(x); }

__device__ __forceinline__ u64 ald(const u64* p){
  return __hip_atomic_load(const_cast<u64*>(p), __ATOMIC_RELAXED, __HIP_MEMORY_SCOPE_AGENT);
}
__device__ __forceinline__ void ast(u64* p, u64 v){
  __hip_atomic_store(p, v, __ATOMIC_RELAXED, __HIP_MEMORY_SCOPE_AGENT);
}
__device__ __forceinline__ u64 packtv(unsigned tag, float v){
  union{ float f; unsigned u; } c; c.f = v;
  return ((u64)tag << 32) | (u64)c.u;
}
__device__ __forceinline__ float unpackv(u64 x){
  union{ unsigned u; float f; } c; c.u = (unsigned)x; return c.f;
}

// 4 f16 MACs: w8/h8 each hold 4 halfs; accumulate into f32.
typedef _Float16 h2_t __attribute__((ext_vector_type(2)));
__device__ __forceinline__ float dot4h(u64 w8, u64 h8, float acc){
#if __has_builtin(__builtin_amdgcn_fdot2)
  union{ u64 x; h2_t v[2]; } cw, ch;
  cw.x = w8; ch.x = h8;
  acc = __builtin_amdgcn_fdot2(cw.v[0], ch.v[0], acc, false);
  acc = __builtin_amdgcn_fdot2(cw.v[1], ch.v[1], acc, false);
#else
  union{ u64 x; __half2 v[2]; } cw, ch;
  cw.x = w8; ch.x = h8;
  float2 a0=__half22float2(cw.v[0]), b0=__half22float2(ch.v[0]);
  float2 a1=__half22float2(cw.v[1]), b1=__half22float2(ch.v[1]);
  acc += a0.x*b0.x + a0.y*b0.y + a1.x*b1.x + a1.y*b1.y;
#endif
  return acc;
}

// fast poll (f16-packed): 2 returning L2 atomics per lane per iteration.
// entry e holds {tag, h[2e],h[2e+1] as half2}; deposits half2 into hu[].
__device__ __forceinline__ bool poll_fast16(u64* base, int lane, unsigned tag,
                                            unsigned* hu, int tries){
  u64* p = base + lane;
  u64 zero = 0;
  for (int i = 0; i < tries; ++i){
    u64 x0, x1;
    asm volatile(
      "global_atomic_add_x2 %0, %2, %4, off sc0\n\t"
      "global_atomic_add_x2 %1, %3, %4, off sc0\n\t"
      "s_waitcnt vmcnt(0)"
      : "=&v"(x0), "=&v"(x1)
      : "v"(p), "v"(p+64), "v"(zero)
      : "memory");
    bool ok = (((unsigned)(x0>>32))==tag) & (((unsigned)(x1>>32))==tag);
    if (__all(ok)){
      hu[lane]      = (unsigned)x0;
      hu[64 + lane] = (unsigned)x1;
      return true;
    }
  }
  return false;
}

// slow poll: agent-scope grouped loads on f32 tagged array; deposit as f16.
__device__ __forceinline__ void poll_slow(const u64* base, int lane, unsigned tag, unsigned* hu){
  __half* hp = (__half*)hu;
  const u64* p = base + lane;
  int guard = 0;
  while (true){
    u64 x0 = ald(p), x1 = ald(p+64), x2 = ald(p+128), x3 = ald(p+192);
    bool ok = (((unsigned)(x0>>32))==tag) & (((unsigned)(x1>>32))==tag)
            & (((unsigned)(x2>>32))==tag) & (((unsigned)(x3>>32))==tag);
    if (ok | (++guard > BAIL)){
      hp[      lane] = __float2half(unpackv(x0));
      hp[ 64 + lane] = __float2half(unpackv(x1));
      hp[128 + lane] = __float2half(unpackv(x2));
      hp[192 + lane] = __float2half(unpackv(x3));
      break;
    }
    if (guard > 2000) __builtin_amdgcn_s_sleep(1);
  }
}

__global__ __launch_bounds__(BT) void fused_kernel(
    const float* __restrict__ v0, const float* __restrict__ m0,
    const float* __restrict__ W1v, const float* __restrict__ b1v,
    const float* __restrict__ W1m, const float* __restrict__ b1m,
    const float* __restrict__ Wih_low, const float* __restrict__ Whh_low,
    const float* __restrict__ bih_low, const float* __restrict__ bhh_low,
    const float* __restrict__ Wih_high, const float* __restrict__ Whh_high,
    const float* __restrict__ bih_high, const float* __restrict__ bhh_high,
    const float* __restrict__ W2v, const float* __restrict__ b2v,
    const float* __restrict__ W2m, const float* __restrict__ b2m,
    float* __restrict__ out,
    u64* h1xf, u64* h2xf, u64* h1xs, u64* h2xs,
    u64* gxt, u64* h1ot, unsigned* ectl)
{
  // weights: 4 mats x 24 rows, row = 64 u64 chunks + 1 pad (bank spread)
  __shared__ u64 wlds8[96*65];                  // 49920 B
  __shared__ alignas(8) unsigned h1u[128];      // h1 as half2 entries
  __shared__ alignas(8) unsigned h2u[128];
  __shared__ float giA_l[24], ghA_l[24], giB_l[24], ghB_l[24];
  __shared__ float gx_lds[48];                  // [par][24]
  __shared__ float xbuf[H];
  __shared__ int s_role, s_idx;

  const int tid = threadIdx.x;
  const int wv = tid >> 6, lane = tid & 63;

  // ---------------- election: find one XCD with >=32 blocks (pigeonhole) ----
  if (tid == 0){
    unsigned xcd;
    asm volatile("s_getreg_b32 %0, hwreg(HW_REG_XCC_ID, 0, 32)" : "=s"(xcd));
    xcd &= 7u;
    unsigned tk = atomicAdd(&ectl[xcd], 1u);
    if (tk == 31u) atomicCAS(&ectl[8], 0u, xcd + 1u);
    unsigned ch; int guard = 0;
    while (!(ch = __hip_atomic_load(&ectl[8], __ATOMIC_RELAXED, __HIP_MEMORY_SCOPE_AGENT))){
      __builtin_amdgcn_s_sleep(2);
      if (++guard > BAIL){ ch = 1u; break; }
    }
    if (xcd == ch - 1u && tk < 32u){ s_role = 0; s_idx = (int)tk; }
    else {
      unsigned ak = atomicAdd(&ectl[9], 1u);
      if      (ak < 50u ){ s_role = 1; s_idx = (int)ak; }
      else if (ak < 100u){ s_role = 2; s_idx = (int)(ak - 50u); }
      else               { s_role = 3; s_idx = 0; }
    }
  }
  __syncthreads();
  const int role = s_role, idx = s_idx;
  if (role == 3) return;

  if (role == 0){
    // ================================================== scan role
    const int b = idx;
    // stage weights: mat m in [0,4): 0=Wih_low[:,256:512] 1=Whh_low 2=Wih_high 3=Whh_high
    for (int i = tid; i < 96*64; i += BT){
      int gr = i >> 6, c = i & 63;
      int m = gr / 24, lr = gr - m*24;
      int gate = lr >> 3, j = lr & 7;
      int row = gate*H + b*HJ + j;
      int k = c*4;
      float4 f;
      if      (m == 0) f = *(const float4*)(Wih_low  + (size_t)row*512 + 256 + k);
      else if (m == 1) f = *(const float4*)(Whh_low  + (size_t)row*256 + k);
      else if (m == 2) f = *(const float4*)(Wih_high + (size_t)row*256 + k);
      else             f = *(const float4*)(Whh_high + (size_t)row*256 + k);
      union{ u64 x; __half2 v[2]; } pk;
      pk.v[0] = __floats2half2_rn(f.x, f.y);
      pk.v[1] = __floats2half2_rn(f.z, f.w);
      wlds8[gr*65 + c] = pk.x;
    }
    if (tid < 24){ giA_l[tid]=0.f; ghA_l[tid]=0.f; giB_l[tid]=0.f; ghB_l[tid]=0.f; }

    float hv1 = 0.f, hv2 = 0.f;
    float blR=0,blZ=0,blN=0, biR=0,biZ=0,biN=0, bhR=0,bhZ=0,bhN=0;
    bool fast_ok1 = true, fast_ok2 = true;    // wave3 latches
    const int jg = b*HJ + lane;               // valid for lane<HJ
    if (wv == 0 && lane < HJ){
      blR = bhh_low [jg]; blZ = bhh_low [H+jg]; blN = bhh_low [2*H+jg];
      biR = bih_high[jg]; biZ = bih_high[H+jg]; biN = bih_high[2*H+jg];
      bhR = bhh_high[jg]; bhZ = bhh_high[H+jg]; bhN = bhh_high[2*H+jg];
      const u64* g = gxt + jg;                // Gx[0] -> gx_lds[0..23]
      int guard = 0;
      while (true){
        u64 a0 = ald(g), a1 = ald(g + H), a2 = ald(g + 2*H);
        bool ok = (((unsigned)(a0>>32))==1u) & (((unsigned)(a1>>32))==1u) & (((unsigned)(a2>>32))==1u);
        if (ok | (++guard > BAIL)){
          gx_lds[lane] = unpackv(a0); gx_lds[8+lane] = unpackv(a1); gx_lds[16+lane] = unpackv(a2);
          break;
        }
        __builtin_amdgcn_s_sleep(4);
      }
    }
    __syncthreads();

    const int gr = wv*16 + (lane >> 2);       // P-phase row (waves 0-2)
    const int q  = lane & 3;

    for (int t = 0; t < T_STEPS; ++t){
      const int par = t & 1;
      const unsigned tag = (unsigned)(t + 1);

      // ---- seg_a: wave0 finalize A + publish | wave1 Gx[t+1] | wave3 poll h1
      if (wv == 0){
        float hnew = hv1;
        if (lane < HJ){
          float giR = giA_l[lane]    + gx_lds[par*24 + lane];
          float giZ = giA_l[8+lane]  + gx_lds[par*24 + 8 + lane];
          float giN = giA_l[16+lane] + gx_lds[par*24 + 16 + lane];
          float ghR = ghA_l[lane]    + blR;
          float ghZ = ghA_l[8+lane]  + blZ;
          float ghN = ghA_l[16+lane] + blN;
          float r = sigm(giR + ghR), z = sigm(giZ + ghZ);
          float n = ftanh(giN + r * ghN);
          hv1 = (1.f - z) * n + z * hv1;
          hnew = hv1;
          ast(h1ot + (size_t)t*H + jg, packtv(1u, hv1));   // cross-XCD to post
        }
        float pa = __shfl(hnew, 2*(lane & 3));
        float pb = __shfl(hnew, 2*(lane & 3) + 1);
        if (lane < 4){
          union{ __half2 hh; unsigned u; } c; c.hh = __floats2half2_rn(pa, pb);
          u64 pk = ((u64)tag << 32) | (u64)c.u;
          u64* df = h1xf + par*128 + (b<<2) + lane;
          #pragma unroll
          for (int cc = 0; cc < NB; ++cc)
            asm volatile("global_atomic_swap_x2 %0, %1, off" :: "v"(df + cc*256), "v"(pk) : "memory");
        }
        if (lane < HJ) ast(h1xs + par*H + jg, packtv(tag, hv1));
      } else if (wv == 1){
        if (lane < HJ && t + 1 < T_STEPS){               // prefetch Gx[t+1]
          const u64* g = gxt + (size_t)(t+1)*G3 + jg;
          int guard = 0;
          while (true){
            u64 a0 = ald(g), a1 = ald(g + H), a2 = ald(g + 2*H);
            bool ok = (((unsigned)(a0>>32))==1u) & (((unsigned)(a1>>32))==1u) & (((unsigned)(a2>>32))==1u);
            if (ok | (++guard > BAIL)){
              int np = (1 - par) * 24;
              gx_lds[np + lane] = unpackv(a0); gx_lds[np + 8 + lane] = unpackv(a1); gx_lds[np + 16 + lane] = unpackv(a2);
              break;
            }
            __builtin_amdgcn_s_sleep(1);
          }
        }
      }
      if (t == T_STEPS - 1) break;
      if (wv == 3){
        bool got = false;
        if (fast_ok1){
          got = poll_fast16(h1xf + b*256 + par*128, lane, tag, h1u, t==0 ? 6000 : 300000);
          fast_ok1 = got;
        }
        if (!got) poll_slow(h1xs + par*H, lane, tag, h1u);
      }
      __syncthreads();                                   // bar1: h1 ready

      // ---- P1: 48 rows on h1: gi_B (mat2) rows 0..23, gh_A' (mat1) rows 24..47
      if (wv < 3){
        int wr = (gr < 24) ? (48 + gr) : gr;             // mat2 base 48, mat1 base 24
        const u64* wrow = wlds8 + wr*65 + q*16;
        const u64* hh = reinterpret_cast<const u64*>(h1u) + q*16;
        float s = 0.f;
        #pragma unroll
        for (int i = 0; i < 16; ++i) s = dot4h(wrow[i], hh[i], s);
        s += __shfl_xor(s, 1);
        s += __shfl_xor(s, 2);
        if (q == 0){ if (gr < 24) giB_l[gr] = s; else ghA_l[gr-24] = s; }
      }
      __syncthreads();                                   // bar2: gi_B/gh_A' ready

      // ---- seg_b: wave0 finalize B + publish | wave3 poll h2
      if (wv == 0){
        float hnew = hv2;
        if (lane < HJ){
          float giR = giB_l[lane]    + biR, ghR = ghB_l[lane]    + bhR;
          float giZ = giB_l[8+lane]  + biZ, ghZ = ghB_l[8+lane]  + bhZ;
          float giN = giB_l[16+lane] + biN, ghN = ghB_l[16+lane] + bhN;
          float r = sigm(giR + ghR), z = sigm(giZ + ghZ);
          float n = ftanh(giN + r * ghN);
          hv2 = (1.f - z) * n + z * hv2;
          hnew = hv2;
        }
        float pa = __shfl(hnew, 2*(lane & 3));
        float pb = __shfl(hnew, 2*(lane & 3) + 1);
        if (lane < 4){
          union{ __half2 hh; unsigned u; } c; c.hh = __floats2half2_rn(pa, pb);
          u64 pk = ((u64)tag << 32) | (u64)c.u;
          u64* df = h2xf + par*128 + (b<<2) + lane;
          #pragma unroll
          for (int cc = 0; cc < NB; ++cc)
            asm volatile("global_atomic_swap_x2 %0, %1, off" :: "v"(df + cc*256), "v"(pk) : "memory");
        }
        if (lane < HJ) ast(h2xs + par*H + jg, packtv(tag, hv2));
      } else if (wv == 3){
        bool got = false;
        if (fast_ok2){
          got = poll_fast16(h2xf + b*256 + par*128, lane, tag, h2u, t==0 ? 6000 : 300000);
          fast_ok2 = got;
        }
        if (!got) poll_slow(h2xs + par*H, lane, tag, h2u);
      }
      __syncthreads();                                   // bar3: h2 ready

      // ---- P2: 48 rows on h2: gi_A' (mat0) rows 0..23, gh_B' (mat3) rows 24..47
      if (wv < 3){
        int wr = (gr < 24) ? gr : (48 + gr);             // mat0 base 0, mat3 base 72
        const u64* wrow = wlds8 + wr*65 + q*16;
        const u64* hh = reinterpret_cast<const u64*>(h2u) + q*16;
        float s = 0.f;
        #pragma unroll
        for (int i = 0; i < 16; ++i) s = dot4h(wrow[i], hh[i], s);
        s += __shfl_xor(s, 1);
        s += __shfl_xor(s, 2);
        if (q == 0){ if (gr < 24) giA_l[gr] = s; else ghB_l[gr-24] = s; }
      }
      __syncthreads();                                   // bar4
    }

  } else if (role == 1){
    // ================================================== featgx role
    const int t = idx;
    { int j = tid >> 1, s = tid & 1;
      const float4* a4 = reinterpret_cast<const float4*>(v0 + (size_t)t*VIN) + s*96;
      const float4* w4 = reinterpret_cast<const float4*>(W1v + (size_t)j*VIN) + s*96;
      float p = 0.f;
      #pragma unroll 4
      for (int c = 0; c < 96; ++c){
        float4 a = a4[c], w = w4[c];
        p += a.x*w.x + a.y*w.y + a.z*w.z + a.w*w.w;
      }
      p += __shfl_xor(p, 1);
      if (s == 0) xbuf[j] = eluf(p + b1v[j]);
    }
    if (tid < VF){
      float am = b1m[tid] + W1m[tid*2]*m0[t*2] + W1m[tid*2+1]*m0[t*2+1];
      xbuf[VF + tid] = eluf(am);
    }
    __syncthreads();
    #pragma unroll
    for (int k = 0; k < 3; ++k){
      int r = k*256 + tid;
      const float4* w4 = reinterpret_cast<const float4*>(Wih_low + (size_t)r*(2*H));
      const float4* x4 = reinterpret_cast<const float4*>(xbuf);
      float acc = bih_low[r];
      #pragma unroll 8
      for (int c = 0; c < 64; ++c){
        float4 w = w4[c], x = x4[c];
        acc += w.x*x.x + w.y*x.y + w.z*x.z + w.w*x.w;
      }
      ast(gxt + (size_t)t*G3 + r, packtv(1u, acc));
    }

  } else {
    // ================================================== post role
    const int t = idx;
    for (int i = 0; i < t; ++i) __builtin_amdgcn_s_sleep(32);   // staggered start
    if (wv == 0){
      const u64* p = h1ot + (size_t)t*H + lane;
      int guard = 0;
      while (true){
        u64 x0 = ald(p), x1 = ald(p+64), x2 = ald(p+128), x3 = ald(p+192);
        bool ok = (((unsigned)(x0>>32))==1u) & (((unsigned)(x1>>32))==1u)
                & (((unsigned)(x2>>32))==1u) & (((unsigned)(x3>>32))==1u);
        if (ok | (++guard > BAIL)){
          xbuf[      lane] = eluf(unpackv(x0));
          xbuf[ 64 + lane] = eluf(unpackv(x1));
          xbuf[128 + lane] = eluf(unpackv(x2));
          xbuf[192 + lane] = eluf(unpackv(x3));
          break;
        }
        __builtin_amdgcn_s_sleep(8);
      }
    }
    __syncthreads();
    #pragma unroll
    for (int k = 0; k < 3; ++k){
      int r = k*256 + tid;
      const float4* w4 = reinterpret_cast<const float4*>(W2v + (size_t)r*VF);
      const float4* f4 = reinterpret_cast<const float4*>(xbuf);
      float acc = b2v[r];
      #pragma unroll 8
      for (int c = 0; c < 32; ++c){
        float4 w = w4[c], x = f4[c];
        acc += w.x*x.x + w.y*x.y + w.z*x.z + w.w*x.w;
      }
      out[(size_t)t*VIN + r] = sigm(acc);
    }
    if (tid < MIN_){
      const float* wm = W2m + tid*VF;
      float am = b2m[tid];
      #pragma unroll 8
      for (int c = 0; c < VF; ++c) am += wm[c] * xbuf[VF + c];
      out[(size_t)T_STEPS*VIN + t*MIN_ + tid] = tanhf(am);
    }
  }
}

extern "C" void kernel_launch(void* const* d_in, const int* in_sizes, int n_in,
                              void* d_out, int out_size, void* d_ws, size_t ws_size,
                              hipStream_t stream)
{
  const float* v0       = (const float*)d_in[0];
  const float* m0       = (const float*)d_in[1];
  const float* W1v      = (const float*)d_in[2];
  const float* b1v      = (const float*)d_in[3];
  const float* W1m      = (const float*)d_in[4];
  const float* b1m      = (const float*)d_in[5];
  const float* Wih_low  = (const float*)d_in[6];
  const float* Whh_low  = (const float*)d_in[7];
  const float* bih_low  = (const float*)d_in[8];
  const float* bhh_low  = (const float*)d_in[9];
  const float* Wih_high = (const float*)d_in[10];
  const float* Whh_high = (const float*)d_in[11];
  const float* bih_high = (const float*)d_in[12];
  const float* bhh_high = (const float*)d_in[13];
  const float* W2v      = (const float*)d_in[14];
  const float* b2v      = (const float*)d_in[15];
  const float* W2m      = (const float*)d_in[16];
  const float* b2m      = (const float*)d_in[17];
  float* out = (float*)d_out;

  // ws layout (8B-aligned). Poison 0xAA..AA != any tag used (1..50).
  // h1xf/h2xf (fast, f16-packed): [copy c][par][128] u64 -> copy c at c*256.
  // h1xs/h2xs (slow, f32 tagged): [par][256] u64, single shared copy.
  char* ws = (char*)d_ws;
  u64* h1xf     = (u64*)(ws + 0);               // 64 KB
  u64* h2xf     = (u64*)(ws + 65536);           // 64 KB
  u64* h1xs     = (u64*)(ws + 131072);          // 4 KB
  u64* h2xs     = (u64*)(ws + 135168);          // 4 KB
  u64* gxt      = (u64*)(ws + 139264);          // 300 KB
  u64* h1ot     = (u64*)(ws + 446464);          // 100 KB
  unsigned* ectl= (unsigned*)(ws + 548864);     // election counters

  hipMemsetAsync(ws + 548864, 0, 256, stream);  // zero election state only

  fused_kernel<<<NBLOCKS, BT, 0, stream>>>(
      v0, m0, W1v, b1v, W1m, b1m,
      Wih_low, Whh_low, bih_low, bhh_low,
      Wih_high, Whh_high, bih_high, bhh_high,
      W2v, b2v, W2m, b2m, out,
      h1xf, h2xf, h1xs, h2xs, gxt, h1ot, ectl);
}